// Round 2
// baseline (715.328 us; speedup 1.0000x reference)
//
#include <hip/hip_runtime.h>
#include <hip/hip_bf16.h>
#include <cstdint>
#include <cstddef>

typedef __bf16 bf16;
typedef __attribute__((ext_vector_type(8))) __bf16 bf16x8;
typedef __attribute__((ext_vector_type(4))) __bf16 bf16x4v;
typedef __attribute__((ext_vector_type(4))) float f32x4;

#define NSEQ 1024
#define NHEAD 16
#define NBATCH 16
#define CDIM 512
#define TBL 3969
#define MTOT (NBATCH*NSEQ)
#define QK_SCALE 0.17677669529663687f

__device__ __forceinline__ f32x4 mfma16(bf16x8 a, bf16x8 b, f32x4 c) {
  return __builtin_amdgcn_mfma_f32_16x16x32_bf16(a, b, c, 0, 0, 0);
}

// ---------------- prep: transpose+split weights, transpose bias table ----------------
__global__ __launch_bounds__(256) void prep_kernel(
    const float* __restrict__ wqkv, const float* __restrict__ wproj,
    const float* __restrict__ btab,
    bf16* __restrict__ wqkvTh, bf16* __restrict__ wqkvTl,
    bf16* __restrict__ wprojTh, bf16* __restrict__ wprojTl,
    float* __restrict__ tableT)
{
  int e = blockIdx.x * 256 + threadIdx.x;
  if (e < 1536 * 512) {
    int n = e >> 9, k = e & 511;
    float v = wqkv[k * 1536 + n];
    bf16 h = (bf16)v;
    wqkvTh[e] = h;
    wqkvTl[e] = (bf16)(v - (float)h);
  } else if (e < 1536 * 512 + 512 * 512) {
    int e2 = e - 1536 * 512;
    int n = e2 >> 9, k = e2 & 511;
    float v = wproj[k * 512 + n];
    bf16 h = (bf16)v;
    wprojTh[e2] = h;
    wprojTl[e2] = (bf16)(v - (float)h);
  } else {
    int e3 = e - (1536 * 512 + 512 * 512);
    if (e3 < NHEAD * TBL) {
      int h = e3 / TBL, i = e3 - h * TBL;
      tableT[e3] = btab[i * 16 + h];
    }
  }
}

// ---------------- split-bf16 GEMM: C[M,N] = A[M,512] @ W + bias ----------------
// MODE 0: N=1536, epilogue routes to Q(scaled)/K as [16384][512] hi/lo and V transposed [bh][d][n]
// MODE 1: N=512,  epilogue writes fp32 out
template<int MODE>
__global__ __launch_bounds__(256) void gemm_kernel(
    const float* __restrict__ A,
    const bf16* __restrict__ BTh, const bf16* __restrict__ BTl,
    const float* __restrict__ bvec,
    bf16* __restrict__ Qh, bf16* __restrict__ Ql,
    bf16* __restrict__ Kh, bf16* __restrict__ Kl,
    bf16* __restrict__ Vth, bf16* __restrict__ Vtl,
    float* __restrict__ out)
{
  constexpr int NT = (MODE == 0) ? 12 : 4;   // column tiles of 128
  __shared__ bf16 Ash[128][40];
  __shared__ bf16 Asl[128][40];
  __shared__ bf16 Bsh[128][40];
  __shared__ bf16 Bsl[128][40];

  const int bx = blockIdx.x % NT;
  const int by = blockIdx.x / NT;
  const int row0 = by * 128, col0 = bx * 128;
  const int tid = threadIdx.x;
  const int lane = tid & 63, wave = tid >> 6;
  const int l15 = lane & 15, l4 = lane >> 4;
  const int wr = wave >> 1, wc = wave & 1;

  f32x4 acc[4][4];
  #pragma unroll
  for (int i = 0; i < 4; ++i)
    #pragma unroll
    for (int j = 0; j < 4; ++j) acc[i][j] = (f32x4){0.f, 0.f, 0.f, 0.f};

  for (int kt = 0; kt < 16; ++kt) {
    // stage A tile [128][32] fp32 -> split bf16 in LDS
    #pragma unroll
    for (int p = 0; p < 4; ++p) {
      int s = tid + p * 256;
      int r = s >> 3, f4 = s & 7;
      f32x4 v = *(const f32x4*)(A + (size_t)(row0 + r) * 512 + kt * 32 + f4 * 4);
      bf16x4v hi, lo;
      #pragma unroll
      for (int j = 0; j < 4; ++j) {
        bf16 h = (bf16)v[j];
        hi[j] = h;
        lo[j] = (bf16)(v[j] - (float)h);
      }
      *(bf16x4v*)&Ash[r][f4 * 4] = hi;
      *(bf16x4v*)&Asl[r][f4 * 4] = lo;
    }
    // stage B tile [128 cols][32 k] from pre-split transposed weights
    #pragma unroll
    for (int p = 0; p < 2; ++p) {
      int s = tid + p * 256;
      int r = s >> 2, c16 = s & 3;
      *(bf16x8*)&Bsh[r][c16 * 8] = *(const bf16x8*)(BTh + (size_t)(col0 + r) * 512 + kt * 32 + c16 * 8);
      *(bf16x8*)&Bsl[r][c16 * 8] = *(const bf16x8*)(BTl + (size_t)(col0 + r) * 512 + kt * 32 + c16 * 8);
    }
    __syncthreads();

    bf16x8 ah[4], al[4], bh[4], bl[4];
    #pragma unroll
    for (int mf = 0; mf < 4; ++mf) {
      int r = wr * 64 + mf * 16 + l15;
      ah[mf] = *(const bf16x8*)&Ash[r][l4 * 8];
      al[mf] = *(const bf16x8*)&Asl[r][l4 * 8];
    }
    #pragma unroll
    for (int nf = 0; nf < 4; ++nf) {
      int c = wc * 64 + nf * 16 + l15;
      bh[nf] = *(const bf16x8*)&Bsh[c][l4 * 8];
      bl[nf] = *(const bf16x8*)&Bsl[c][l4 * 8];
    }
    #pragma unroll
    for (int mf = 0; mf < 4; ++mf)
      #pragma unroll
      for (int nf = 0; nf < 4; ++nf) {
        f32x4 a = acc[mf][nf];
        a = mfma16(ah[mf], bh[nf], a);
        a = mfma16(ah[mf], bl[nf], a);
        a = mfma16(al[mf], bh[nf], a);
        acc[mf][nf] = a;
      }
    __syncthreads();
  }

  // epilogue
  #pragma unroll
  for (int mf = 0; mf < 4; ++mf) {
    #pragma unroll
    for (int nf = 0; nf < 4; ++nf) {
      int colb = col0 + wc * 64 + nf * 16 + l15;
      float bb = bvec[colb];
      #pragma unroll
      for (int i = 0; i < 4; ++i) {
        int m = row0 + wr * 64 + mf * 16 + l4 * 4 + i;
        float v = acc[mf][nf][i] + bb;
        if (MODE == 1) {
          out[(size_t)m * 512 + colb] = v;
        } else {
          int t = colb >> 9, cc = colb & 511;
          if (t == 0) {
            v *= QK_SCALE;
            bf16 h = (bf16)v;
            Qh[(size_t)m * 512 + cc] = h;
            Ql[(size_t)m * 512 + cc] = (bf16)(v - (float)h);
          } else if (t == 1) {
            bf16 h = (bf16)v;
            Kh[(size_t)m * 512 + cc] = h;
            Kl[(size_t)m * 512 + cc] = (bf16)(v - (float)h);
          } else {
            int b = m >> 10, n = m & 1023, hh = cc >> 5, d = cc & 31;
            size_t a = ((size_t)((b * 16 + hh) * 32 + d)) * 1024 + n;
            bf16 h = (bf16)v;
            Vth[a] = h;
            Vtl[a] = (bf16)(v - (float)h);
          }
        }
      }
    }
  }
}

// ---------------- fused flash attention with analytic relative-position bias ----------------
// grid: 4096 = qt(16) | h(16) | b(16); block: 4 waves, each owns 16 q rows.
__global__ __launch_bounds__(256) void attn_kernel(
    const bf16* __restrict__ Qh, const bf16* __restrict__ Ql,
    const bf16* __restrict__ Kh, const bf16* __restrict__ Kl,
    const bf16* __restrict__ Vth, const bf16* __restrict__ Vtl,
    const float* __restrict__ tableT,
    float* __restrict__ attn_out)
{
  __shared__ float tbl[TBL];
  __shared__ bf16 Pt[4][16][72];   // per-wave P tile, +8 pad
  const int bid = blockIdx.x;
  const int qt = bid & 15, h = (bid >> 4) & 15, b = bid >> 8;
  const int tid = threadIdx.x, lane = tid & 63, wave = tid >> 6;
  const int l15 = lane & 15, l4 = lane >> 4;

  for (int i = tid; i < TBL; i += 256) tbl[i] = tableT[h * TBL + i];
  __syncthreads();

  const int q0 = qt * 64 + wave * 16;
  const size_t mrow = (size_t)b * 1024 + q0;
  const size_t qoff = (mrow + l15) * 512 + h * 32 + l4 * 8;
  const bf16x8 qfh = *(const bf16x8*)(Qh + qoff);
  const bf16x8 qfl = *(const bf16x8*)(Ql + qoff);

  float mrun[4], srun[4];
  int basei[4];
  f32x4 O0 = {0, 0, 0, 0}, O1 = {0, 0, 0, 0};
  #pragma unroll
  for (int i = 0; i < 4; ++i) {
    int qi = q0 + l4 * 4 + i;
    basei[i] = ((qi >> 5) + 31) * 63 + (qi & 31) + 31;
    mrun[i] = -1e30f;
    srun[i] = 0.f;
  }

  const size_t kbase = ((size_t)b * 1024) * 512 + h * 32;
  const size_t vbase = ((size_t)(b * 16 + h) * 32) * 1024;

  for (int t0 = 0; t0 < 1024; t0 += 64) {
    // S = Q K^T (split bf16, fp32 accum), fragments straight from global (L2-resident)
    f32x4 S[4];
    #pragma unroll
    for (int nf = 0; nf < 4; ++nf) {
      size_t ko = kbase + (size_t)(t0 + nf * 16 + l15) * 512 + l4 * 8;
      bf16x8 kfh = *(const bf16x8*)(Kh + ko);
      bf16x8 kfl = *(const bf16x8*)(Kl + ko);
      f32x4 s = {0, 0, 0, 0};
      s = mfma16(qfh, kfh, s);
      s = mfma16(qfh, kfl, s);
      s = mfma16(qfl, kfh, s);
      S[nf] = s;
    }
    // analytic relative-position bias from LDS table
    #pragma unroll
    for (int nf = 0; nf < 4; ++nf) {
      int kvj = t0 + nf * 16 + l15;
      int yj63 = (kvj >> 5) * 63, xj = kvj & 31;
      #pragma unroll
      for (int i = 0; i < 4; ++i)
        S[nf][i] += tbl[basei[i] - yj63 - xj];
    }
    // online softmax (rows live in 16-lane groups; xor-shuffles stay in-group)
    #pragma unroll
    for (int i = 0; i < 4; ++i) {
      float m0 = fmaxf(fmaxf(S[0][i], S[1][i]), fmaxf(S[2][i], S[3][i]));
      m0 = fmaxf(m0, __shfl_xor(m0, 1));
      m0 = fmaxf(m0, __shfl_xor(m0, 2));
      m0 = fmaxf(m0, __shfl_xor(m0, 4));
      m0 = fmaxf(m0, __shfl_xor(m0, 8));
      float mn = fmaxf(mrun[i], m0);
      float f = __expf(mrun[i] - mn);
      mrun[i] = mn;
      srun[i] *= f;
      O0[i] *= f;
      O1[i] *= f;
    }
    float rsum[4] = {0, 0, 0, 0};
    #pragma unroll
    for (int nf = 0; nf < 4; ++nf)
      #pragma unroll
      for (int i = 0; i < 4; ++i) {
        float p = __expf(S[nf][i] - mrun[i]);
        S[nf][i] = p;
        rsum[i] += p;
      }
    #pragma unroll
    for (int i = 0; i < 4; ++i) {
      float r = rsum[i];
      r += __shfl_xor(r, 1);
      r += __shfl_xor(r, 2);
      r += __shfl_xor(r, 4);
      r += __shfl_xor(r, 8);
      srun[i] += r;
    }
    // D-layout -> A-layout via per-wave LDS round-trip
    #pragma unroll
    for (int nf = 0; nf < 4; ++nf)
      #pragma unroll
      for (int i = 0; i < 4; ++i)
        Pt[wave][l4 * 4 + i][nf * 16 + l15] = (bf16)S[nf][i];
    __syncthreads();
    // O += P @ V (V hi/lo from transposed global layout, contiguous b128 per lane)
    #pragma unroll
    for (int ks = 0; ks < 2; ++ks) {
      bf16x8 pf = *(const bf16x8*)&Pt[wave][l15][ks * 32 + l4 * 8];
      #pragma unroll
      for (int nd = 0; nd < 2; ++nd) {
        size_t vo = vbase + (size_t)(nd * 16 + l15) * 1024 + t0 + ks * 32 + l4 * 8;
        bf16x8 vfh = *(const bf16x8*)(Vth + vo);
        bf16x8 vfl = *(const bf16x8*)(Vtl + vo);
        if (nd == 0) {
          O0 = mfma16(pf, vfh, O0);
          O0 = mfma16(pf, vfl, O0);
        } else {
          O1 = mfma16(pf, vfh, O1);
          O1 = mfma16(pf, vfl, O1);
        }
      }
    }
  }

  #pragma unroll
  for (int i = 0; i < 4; ++i) {
    float inv = 1.f / srun[i];
    size_t ro = (mrow + l4 * 4 + i) * 512 + h * 32;
    attn_out[ro + l15] = O0[i] * inv;
    attn_out[ro + 16 + l15] = O1[i] * inv;
  }
}

// ---------------- launch ----------------
extern "C" void kernel_launch(void* const* d_in, const int* in_sizes, int n_in,
                              void* d_out, int out_size, void* d_ws, size_t ws_size,
                              hipStream_t stream) {
  const float* x     = (const float*)d_in[0];
  const float* wqkv  = (const float*)d_in[1];
  const float* bqkv  = (const float*)d_in[2];
  const float* wproj = (const float*)d_in[3];
  const float* bproj = (const float*)d_in[4];
  const float* btab  = (const float*)d_in[5];
  // d_in[6] rel_index: unused, index computed analytically in-kernel
  float* out = (float*)d_out;

  char* ws = (char*)d_ws;
  size_t off = 0;
  auto walloc = [&](size_t bytes) {
    void* p = ws + off;
    off += (bytes + 255) & ~(size_t)255;
    return p;
  };
  bf16* wqkvTh = (bf16*)walloc((size_t)1536 * 512 * 2);
  bf16* wqkvTl = (bf16*)walloc((size_t)1536 * 512 * 2);
  bf16* wprojTh = (bf16*)walloc((size_t)512 * 512 * 2);
  bf16* wprojTl = (bf16*)walloc((size_t)512 * 512 * 2);
  float* tableT = (float*)walloc((size_t)NHEAD * TBL * 4);
  bf16* Qh  = (bf16*)walloc((size_t)MTOT * 512 * 2);
  bf16* Ql  = (bf16*)walloc((size_t)MTOT * 512 * 2);
  bf16* Kh  = (bf16*)walloc((size_t)MTOT * 512 * 2);
  bf16* Kl  = (bf16*)walloc((size_t)MTOT * 512 * 2);
  bf16* Vth = (bf16*)walloc((size_t)MTOT * 512 * 2);
  bf16* Vtl = (bf16*)walloc((size_t)MTOT * 512 * 2);
  float* attn_out = (float*)walloc((size_t)MTOT * 512 * 4);

  const int prep_total = 1536 * 512 + 512 * 512 + NHEAD * TBL;
  prep_kernel<<<(prep_total + 255) / 256, 256, 0, stream>>>(
      wqkv, wproj, btab, wqkvTh, wqkvTl, wprojTh, wprojTl, tableT);

  gemm_kernel<0><<<12 * 128, 256, 0, stream>>>(
      x, wqkvTh, wqkvTl, bqkv, Qh, Ql, Kh, Kl, Vth, Vtl, nullptr);

  attn_kernel<<<4096, 256, 0, stream>>>(Qh, Ql, Kh, Kl, Vth, Vtl, tableT, attn_out);

  gemm_kernel<1><<<4 * 128, 256, 0, stream>>>(
      attn_out, wprojTh, wprojTl, bproj,
      nullptr, nullptr, nullptr, nullptr, nullptr, nullptr, out);
}

// Round 3
// 419.980 us; speedup vs baseline: 1.7032x; 1.7032x over previous
//
#include <hip/hip_runtime.h>
#include <hip/hip_bf16.h>
#include <cstdint>
#include <cstddef>

typedef __bf16 bf16;
typedef __attribute__((ext_vector_type(8))) __bf16 bf16x8;
typedef __attribute__((ext_vector_type(4))) __bf16 bf16x4v;
typedef __attribute__((ext_vector_type(4))) float f32x4;

#define NSEQ 1024
#define NHEAD 16
#define NBATCH 16
#define CDIM 512
#define TBL 3969
#define TBLP 3976   // padded stride (multiple of 8 -> 16B-aligned bf16 rows)
#define MTOT (NBATCH*NSEQ)
#define QK_SCALE 0.17677669529663687f

__device__ __forceinline__ f32x4 mfma16(bf16x8 a, bf16x8 b, f32x4 c) {
  return __builtin_amdgcn_mfma_f32_16x16x32_bf16(a, b, c, 0, 0, 0);
}

// ---------------- prep: transpose+split weights, transpose bias table (bf16) ----------------
__global__ __launch_bounds__(256) void prep_kernel(
    const float* __restrict__ wqkv, const float* __restrict__ wproj,
    const float* __restrict__ btab,
    bf16* __restrict__ wqkvTh, bf16* __restrict__ wqkvTl,
    bf16* __restrict__ wprojTh, bf16* __restrict__ wprojTl,
    bf16* __restrict__ tableT)
{
  int e = blockIdx.x * 256 + threadIdx.x;
  if (e < 1536 * 512) {
    int n = e >> 9, k = e & 511;
    float v = wqkv[k * 1536 + n];
    bf16 h = (bf16)v;
    wqkvTh[e] = h;
    wqkvTl[e] = (bf16)(v - (float)h);
  } else if (e < 1536 * 512 + 512 * 512) {
    int e2 = e - 1536 * 512;
    int n = e2 >> 9, k = e2 & 511;
    float v = wproj[k * 512 + n];
    bf16 h = (bf16)v;
    wprojTh[e2] = h;
    wprojTl[e2] = (bf16)(v - (float)h);
  } else {
    int e3 = e - (1536 * 512 + 512 * 512);
    if (e3 < NHEAD * TBL) {
      int h = e3 / TBL, i = e3 - h * TBL;
      tableT[h * TBLP + i] = (bf16)btab[i * 16 + h];
    }
  }
}

// ---------------- split-bf16 GEMM: C[M,N] = A[M,512] @ W + bias ----------------
// MODE 0: N=1536, epilogue -> Q(scaled) hi/lo, K bf16, V bf16 transposed [bh][d][n]
// MODE 1: N=512,  epilogue -> fp32 out
template<int MODE>
__global__ __launch_bounds__(256) void gemm_kernel(
    const float* __restrict__ A,
    const bf16* __restrict__ BTh, const bf16* __restrict__ BTl,
    const float* __restrict__ bvec,
    bf16* __restrict__ Qh, bf16* __restrict__ Ql,
    bf16* __restrict__ Kh, bf16* __restrict__ Vth,
    float* __restrict__ out)
{
  constexpr int NT = (MODE == 0) ? 12 : 4;   // column tiles of 128
  __shared__ bf16 Ash[128][40];
  __shared__ bf16 Asl[128][40];
  __shared__ bf16 Bsh[128][40];
  __shared__ bf16 Bsl[128][40];

  const int bx = blockIdx.x % NT;
  const int by = blockIdx.x / NT;
  const int row0 = by * 128, col0 = bx * 128;
  const int tid = threadIdx.x;
  const int lane = tid & 63, wave = tid >> 6;
  const int l15 = lane & 15, l4 = lane >> 4;
  const int wr = wave >> 1, wc = wave & 1;

  f32x4 acc[4][4];
  #pragma unroll
  for (int i = 0; i < 4; ++i)
    #pragma unroll
    for (int j = 0; j < 4; ++j) acc[i][j] = (f32x4){0.f, 0.f, 0.f, 0.f};

  for (int kt = 0; kt < 16; ++kt) {
    // stage A tile [128][32] fp32 -> split bf16 in LDS
    #pragma unroll
    for (int p = 0; p < 4; ++p) {
      int s = tid + p * 256;
      int r = s >> 3, f4 = s & 7;
      f32x4 v = *(const f32x4*)(A + (size_t)(row0 + r) * 512 + kt * 32 + f4 * 4);
      bf16x4v hi, lo;
      #pragma unroll
      for (int j = 0; j < 4; ++j) {
        bf16 h = (bf16)v[j];
        hi[j] = h;
        lo[j] = (bf16)(v[j] - (float)h);
      }
      *(bf16x4v*)&Ash[r][f4 * 4] = hi;
      *(bf16x4v*)&Asl[r][f4 * 4] = lo;
    }
    // stage B tile [128 cols][32 k] from pre-split transposed weights
    #pragma unroll
    for (int p = 0; p < 2; ++p) {
      int s = tid + p * 256;
      int r = s >> 2, c16 = s & 3;
      *(bf16x8*)&Bsh[r][c16 * 8] = *(const bf16x8*)(BTh + (size_t)(col0 + r) * 512 + kt * 32 + c16 * 8);
      *(bf16x8*)&Bsl[r][c16 * 8] = *(const bf16x8*)(BTl + (size_t)(col0 + r) * 512 + kt * 32 + c16 * 8);
    }
    __syncthreads();

    bf16x8 ah[4], al[4], bh[4], bl[4];
    #pragma unroll
    for (int mf = 0; mf < 4; ++mf) {
      int r = wr * 64 + mf * 16 + l15;
      ah[mf] = *(const bf16x8*)&Ash[r][l4 * 8];
      al[mf] = *(const bf16x8*)&Asl[r][l4 * 8];
    }
    #pragma unroll
    for (int nf = 0; nf < 4; ++nf) {
      int c = wc * 64 + nf * 16 + l15;
      bh[nf] = *(const bf16x8*)&Bsh[c][l4 * 8];
      bl[nf] = *(const bf16x8*)&Bsl[c][l4 * 8];
    }
    #pragma unroll
    for (int mf = 0; mf < 4; ++mf)
      #pragma unroll
      for (int nf = 0; nf < 4; ++nf) {
        f32x4 a = acc[mf][nf];
        a = mfma16(ah[mf], bh[nf], a);
        a = mfma16(ah[mf], bl[nf], a);
        a = mfma16(al[mf], bh[nf], a);
        acc[mf][nf] = a;
      }
    __syncthreads();
  }

  // epilogue
  #pragma unroll
  for (int mf = 0; mf < 4; ++mf) {
    #pragma unroll
    for (int nf = 0; nf < 4; ++nf) {
      int colb = col0 + wc * 64 + nf * 16 + l15;
      float bb = bvec[colb];
      #pragma unroll
      for (int i = 0; i < 4; ++i) {
        int m = row0 + wr * 64 + mf * 16 + l4 * 4 + i;
        float v = acc[mf][nf][i] + bb;
        if (MODE == 1) {
          out[(size_t)m * 512 + colb] = v;
        } else {
          int t = colb >> 9, cc = colb & 511;
          if (t == 0) {
            v *= QK_SCALE;
            bf16 h = (bf16)v;
            Qh[(size_t)m * 512 + cc] = h;
            Ql[(size_t)m * 512 + cc] = (bf16)(v - (float)h);
          } else if (t == 1) {
            Kh[(size_t)m * 512 + cc] = (bf16)v;
          } else {
            int b = m >> 10, n = m & 1023, hh = cc >> 5, d = cc & 31;
            size_t a = ((size_t)((b * 16 + hh) * 32 + d)) * 1024 + n;
            Vth[a] = (bf16)v;
          }
        }
      }
    }
  }
}

// ---------------- fused flash attention, swapped QK^T, no-max softmax ----------------
// grid: 4096 = qt(16) | h(16) | b(16); block: 4 independent waves, each owns 16 q rows.
__global__ __launch_bounds__(256) void attn_kernel(
    const bf16* __restrict__ Qh, const bf16* __restrict__ Ql,
    const bf16* __restrict__ Kh, const bf16* __restrict__ Vth,
    const bf16* __restrict__ tblg,
    float* __restrict__ attn_out)
{
  __shared__ bf16 tbl[TBL];
  __shared__ bf16 Pt[4][16][72];   // per-wave P tile [q=16][kv=64], stride 72
  const int bid = blockIdx.x;
  const int qt = bid & 15, h = (bid >> 4) & 15, b = bid >> 8;
  const int tid = threadIdx.x, lane = tid & 63, wave = tid >> 6;
  const int l15 = lane & 15, l4 = lane >> 4;

  // stage per-head bias table (bf16, 7938 B)
  {
    const ushort* src = (const ushort*)(tblg + h * TBLP);
    ushort* dst = (ushort*)tbl;
    for (int i = tid; i < 496; i += 256)
      *(uint4*)(dst + i * 8) = *(const uint4*)(src + i * 8);
    if (tid == 0) dst[3968] = src[3968];
  }
  __syncthreads();   // the only block barrier

  const int q0 = qt * 64 + wave * 16;
  const size_t mrow = (size_t)b * 1024 + q0;
  const size_t qoff = (mrow + l15) * 512 + h * 32 + l4 * 8;
  const bf16x8 qfh = *(const bf16x8*)(Qh + qoff);
  const bf16x8 qfl = *(const bf16x8*)(Ql + qoff);

  const int qv = q0 + l15;
  const int base_q = ((qv >> 5) + 31) * 63 + (qv & 31) + 31;

  const size_t kbase = ((size_t)b * 1024) * 512 + h * 32;
  const size_t vbase = ((size_t)(b * 16 + h) * 32) * 1024;

  // prologue loads (tile 0)
  bf16x8 kf[4], vf[4];
  #pragma unroll
  for (int nf = 0; nf < 4; ++nf)
    kf[nf] = *(const bf16x8*)(Kh + kbase + (size_t)(nf * 16 + l15) * 512 + l4 * 8);
  #pragma unroll
  for (int j = 0; j < 4; ++j) {
    int ks = j >> 1, nd = j & 1;
    vf[j] = *(const bf16x8*)(Vth + vbase + (size_t)(nd * 16 + l15) * 1024 + ks * 32 + l4 * 8);
  }

  float rsum = 0.f;
  f32x4 O0 = {0, 0, 0, 0}, O1 = {0, 0, 0, 0};

  for (int t0 = 0; t0 < 1024; t0 += 64) {
    const int tn = (t0 + 64) & 1023;   // wrapped prefetch index (last iter unused)
    // S^T = K · (Qh + Ql): lane holds kv = t0+nf*16+l4*4+i for q row l15
    f32x4 S[4];
    #pragma unroll
    for (int nf = 0; nf < 4; ++nf) {
      f32x4 s = mfma16(kf[nf], qfh, (f32x4){0.f, 0.f, 0.f, 0.f});
      S[nf] = mfma16(kf[nf], qfl, s);
    }
    // prefetch next K tile (hides under softmax VALU)
    bf16x8 kf2[4];
    #pragma unroll
    for (int nf = 0; nf < 4; ++nf)
      kf2[nf] = *(const bf16x8*)(Kh + kbase + (size_t)(tn + nf * 16 + l15) * 512 + l4 * 8);

    // bias + exp (no max subtraction: shift-invariant, S bounded) + pack
    #pragma unroll
    for (int nf = 0; nf < 4; ++nf) {
      int kv0 = t0 + nf * 16 + l4 * 4;
      int idx0 = base_q - ((kv0 >> 5) * 63 + (kv0 & 31));
      bf16x4v pk;
      #pragma unroll
      for (int i = 0; i < 4; ++i) {
        float sv = S[nf][i] + (float)tbl[idx0 - i];
        float p = __expf(sv);
        rsum += p;
        pk[i] = (bf16)p;
      }
      *(bf16x4v*)&Pt[wave][l15][nf * 16 + l4 * 4] = pk;
    }
    // A-fragment of P (per-wave LDS, same-wave ordering only)
    bf16x8 pf0 = *(const bf16x8*)&Pt[wave][l15][l4 * 8];
    bf16x8 pf1 = *(const bf16x8*)&Pt[wave][l15][32 + l4 * 8];
    // prefetch next V tile
    bf16x8 vf2[4];
    #pragma unroll
    for (int j = 0; j < 4; ++j) {
      int ks = j >> 1, nd = j & 1;
      vf2[j] = *(const bf16x8*)(Vth + vbase + (size_t)(nd * 16 + l15) * 1024 + tn + ks * 32 + l4 * 8);
    }
    // O += P @ V
    O0 = mfma16(pf0, vf[0], O0);
    O1 = mfma16(pf0, vf[1], O1);
    O0 = mfma16(pf1, vf[2], O0);
    O1 = mfma16(pf1, vf[3], O1);

    #pragma unroll
    for (int nf = 0; nf < 4; ++nf) kf[nf] = kf2[nf];
    #pragma unroll
    for (int j = 0; j < 4; ++j) vf[j] = vf2[j];
  }

  // single end-of-kernel row-sum reduction across the 4 l4 groups
  rsum += __shfl_xor(rsum, 16);
  rsum += __shfl_xor(rsum, 32);
  #pragma unroll
  for (int i = 0; i < 4; ++i) {
    float rt = __shfl(rsum, l4 * 4 + i);   // lane (l4*4+i) holds total for q row l4*4+i
    float inv = 1.f / rt;
    size_t ro = (mrow + l4 * 4 + i) * 512 + h * 32;
    attn_out[ro + l15] = O0[i] * inv;
    attn_out[ro + 16 + l15] = O1[i] * inv;
  }
}

// ---------------- launch ----------------
extern "C" void kernel_launch(void* const* d_in, const int* in_sizes, int n_in,
                              void* d_out, int out_size, void* d_ws, size_t ws_size,
                              hipStream_t stream) {
  const float* x     = (const float*)d_in[0];
  const float* wqkv  = (const float*)d_in[1];
  const float* bqkv  = (const float*)d_in[2];
  const float* wproj = (const float*)d_in[3];
  const float* bproj = (const float*)d_in[4];
  const float* btab  = (const float*)d_in[5];
  // d_in[6] rel_index: unused, index computed analytically in-kernel
  float* out = (float*)d_out;

  char* ws = (char*)d_ws;
  size_t off = 0;
  auto walloc = [&](size_t bytes) {
    void* p = ws + off;
    off += (bytes + 255) & ~(size_t)255;
    return p;
  };
  bf16* wqkvTh  = (bf16*)walloc((size_t)1536 * 512 * 2);
  bf16* wqkvTl  = (bf16*)walloc((size_t)1536 * 512 * 2);
  bf16* wprojTh = (bf16*)walloc((size_t)512 * 512 * 2);
  bf16* wprojTl = (bf16*)walloc((size_t)512 * 512 * 2);
  bf16* tableT  = (bf16*)walloc((size_t)NHEAD * TBLP * 2);
  bf16* Qh  = (bf16*)walloc((size_t)MTOT * 512 * 2);
  bf16* Ql  = (bf16*)walloc((size_t)MTOT * 512 * 2);
  bf16* Kh  = (bf16*)walloc((size_t)MTOT * 512 * 2);
  bf16* Vth = (bf16*)walloc((size_t)MTOT * 512 * 2);
  float* attn_out = (float*)walloc((size_t)MTOT * 512 * 4);

  const int prep_total = 1536 * 512 + 512 * 512 + NHEAD * TBL;
  prep_kernel<<<(prep_total + 255) / 256, 256, 0, stream>>>(
      wqkv, wproj, btab, wqkvTh, wqkvTl, wprojTh, wprojTl, tableT);

  gemm_kernel<0><<<12 * 128, 256, 0, stream>>>(
      x, wqkvTh, wqkvTl, bqkv, Qh, Ql, Kh, Vth, nullptr);

  attn_kernel<<<4096, 256, 0, stream>>>(Qh, Ql, Kh, Vth, tableT, attn_out);

  gemm_kernel<1><<<4 * 128, 256, 0, stream>>>(
      attn_out, wprojTh, wprojTl, bproj,
      nullptr, nullptr, nullptr, nullptr, out);
}